// Round 1
// baseline (1660.193 us; speedup 1.0000x reference)
//
#include <hip/hip_runtime.h>

#define C 128
#define NEG_SLOPE 0.2f
#define SM_EPS 1e-16f

// ---- monotone uint encoding for float atomicMax ----
static __device__ __forceinline__ unsigned int f2ord(float f) {
    unsigned int u = __float_as_uint(f);
    return (u & 0x80000000u) ? ~u : (u | 0x80000000u);
}
static __device__ __forceinline__ float ord2f(unsigned int k) {
    unsigned int u = (k & 0x80000000u) ? (k ^ 0x80000000u) : ~k;
    return __uint_as_float(u);
}

// ---- init kernels (ws/out are poisoned 0xAA before every launch) ----
__global__ void node_init_kernel(unsigned int* __restrict__ m_bits,
                                 float* __restrict__ denom, int N) {
    int i = blockIdx.x * blockDim.x + threadIdx.x;
    if (i < N) { m_bits[i] = 0u; denom[i] = 0.f; }
}

__global__ void out_init_kernel(float* __restrict__ out,
                                const float* __restrict__ bias, int n) {
    int i = blockIdx.x * blockDim.x + threadIdx.x;
    if (i < n) out[i] = bias[i & (C - 1)];
}

// ---- fused GEMM (h = x @ W) + alpha_s/alpha_d reductions ----
// block: 256 threads; tile: 64 rows x 128 cols; per-thread 8 rows x 4 cols.
// tcol = tid & 31 -> cols tcol*4..+3 ; trow = tid >> 5 -> rows trow*8..+7
__global__ __launch_bounds__(256) void gemm_alpha_kernel(
    const float* __restrict__ x, const float* __restrict__ W,
    const float* __restrict__ a_src, const float* __restrict__ a_dst,
    float* __restrict__ h, float* __restrict__ as_out, float* __restrict__ ad_out,
    int N)
{
    __shared__ float Wl[32 * 128];   // [k][c], 16 KB
    __shared__ float Xl[32 * 68];    // [k][row], pitch 68 (bank-spread + 16B-aligned)

    const int tid  = threadIdx.x;
    const int tcol = tid & 31;
    const int trow = tid >> 5;
    const int row0 = blockIdx.x * 64;

    float acc[8][4];
    #pragma unroll
    for (int r = 0; r < 8; ++r)
        #pragma unroll
        for (int c = 0; c < 4; ++c) acc[r][c] = 0.f;

    for (int kc = 0; kc < 4; ++kc) {
        __syncthreads();
        // stage W chunk [32 x 128], coalesced
        for (int i = tid; i < 32 * 128; i += 256) {
            int k = i >> 7, c = i & 127;
            Wl[i] = W[(kc * 32 + k) * C + c];
        }
        // stage x chunk transposed: Xl[k][row]
        for (int i = tid; i < 64 * 32; i += 256) {
            int r = i >> 5, k = i & 31;
            int row = row0 + r;
            Xl[k * 68 + r] = (row < N) ? x[(size_t)row * C + kc * 32 + k] : 0.f;
        }
        __syncthreads();

        #pragma unroll
        for (int k = 0; k < 32; ++k) {
            float4 wv = *(const float4*)&Wl[k * 128 + (tcol << 2)];
            float4 x0 = *(const float4*)&Xl[k * 68 + (trow << 3)];
            float4 x1 = *(const float4*)&Xl[k * 68 + (trow << 3) + 4];
            float xr[8] = {x0.x, x0.y, x0.z, x0.w, x1.x, x1.y, x1.z, x1.w};
            #pragma unroll
            for (int r = 0; r < 8; ++r) {
                acc[r][0] += xr[r] * wv.x;
                acc[r][1] += xr[r] * wv.y;
                acc[r][2] += xr[r] * wv.z;
                acc[r][3] += xr[r] * wv.w;
            }
        }
    }

    // store h (coalesced float4)
    #pragma unroll
    for (int r = 0; r < 8; ++r) {
        int row = row0 + (trow << 3) + r;
        if (row < N) {
            float4 v = make_float4(acc[r][0], acc[r][1], acc[r][2], acc[r][3]);
            *(float4*)&h[(size_t)row * C + (tcol << 2)] = v;
        }
    }

    // fused alpha reductions: per-row dot with a_src / a_dst
    float4 asv = *(const float4*)&a_src[tcol << 2];
    float4 adv = *(const float4*)&a_dst[tcol << 2];
    #pragma unroll
    for (int r = 0; r < 8; ++r) {
        float ps = acc[r][0] * asv.x + acc[r][1] * asv.y + acc[r][2] * asv.z + acc[r][3] * asv.w;
        float pd = acc[r][0] * adv.x + acc[r][1] * adv.y + acc[r][2] * adv.z + acc[r][3] * adv.w;
        #pragma unroll
        for (int off = 16; off > 0; off >>= 1) {
            ps += __shfl_down(ps, off, 32);
            pd += __shfl_down(pd, off, 32);
        }
        int row = row0 + (trow << 3) + r;
        if (tcol == 0 && row < N) { as_out[row] = ps; ad_out[row] = pd; }
    }
}

// ---- edge pass 1: e = leaky_relu(as[src] + ad[dst]); segment max(dst) ----
__global__ void edge_max_kernel(const int* __restrict__ src, const int* __restrict__ dst,
                                const float* __restrict__ as, const float* __restrict__ ad,
                                float* __restrict__ e_buf, unsigned int* __restrict__ m_bits,
                                int E, int total)
{
    int i = blockIdx.x * blockDim.x + threadIdx.x;
    if (i >= total) return;
    int s = (i < E) ? src[i] : (i - E);
    int d = (i < E) ? dst[i] : (i - E);
    float e = as[s] + ad[d];
    e = (e > 0.f) ? e : NEG_SLOPE * e;
    e_buf[i] = e;
    atomicMax(&m_bits[d], f2ord(e));
}

// ---- edge pass 2: ex = exp(e - m[dst]); segment sum(dst) ----
__global__ void edge_exp_kernel(const int* __restrict__ src, const int* __restrict__ dst,
                                float* __restrict__ e_buf,
                                const unsigned int* __restrict__ m_bits,
                                float* __restrict__ denom, int E, int total)
{
    int i = blockIdx.x * blockDim.x + threadIdx.x;
    if (i >= total) return;
    int d = (i < E) ? dst[i] : (i - E);
    float m = ord2f(m_bits[d]);
    float ex = __expf(e_buf[i] - m);
    e_buf[i] = ex;
    atomicAdd(&denom[d], ex);
}

// ---- edge pass 3: out[dst] += h[src] * (ex / (denom[dst]+eps)) ----
// one wave (64 lanes) per edge, 2 channels per lane
__global__ __launch_bounds__(256) void aggregate_kernel(
    const int* __restrict__ src, const int* __restrict__ dst,
    const float* __restrict__ h, const float* __restrict__ e_buf,
    const float* __restrict__ denom, float* __restrict__ out,
    int E, int total)
{
    long long gid = (long long)blockIdx.x * blockDim.x + threadIdx.x;
    int i = (int)(gid >> 6);
    int c = ((int)gid & 63) << 1;
    if (i >= total) return;
    int s = (i < E) ? src[i] : (i - E);
    int d = (i < E) ? dst[i] : (i - E);
    float coef = e_buf[i] / (denom[d] + SM_EPS);
    float2 hv = *(const float2*)&h[(size_t)s * C + c];
    atomicAdd(&out[(size_t)d * C + c], hv.x * coef);
    atomicAdd(&out[(size_t)d * C + c + 1], hv.y * coef);
}

__global__ void relu_kernel(float* __restrict__ out, int n) {
    int i = blockIdx.x * blockDim.x + threadIdx.x;
    if (i < n) out[i] = fmaxf(out[i], 0.f);
}

extern "C" void kernel_launch(void* const* d_in, const int* in_sizes, int n_in,
                              void* d_out, int out_size, void* d_ws, size_t ws_size,
                              hipStream_t stream) {
    const float* x     = (const float*)d_in[0];
    const float* W     = (const float*)d_in[1];
    const float* a_src = (const float*)d_in[2];
    const float* a_dst = (const float*)d_in[3];
    const float* bias  = (const float*)d_in[4];
    const int*   edge  = (const int*)d_in[5];

    const int N = in_sizes[0] / C;
    const int E = in_sizes[5] / 2;
    const int total = E + N;                 // edges + self loops
    const int* src = edge;
    const int* dst = edge + E;
    float* out = (float*)d_out;

    // workspace layout (floats): h[N*C] | e_buf[E+N] | as[N] | ad[N] | m_bits[N] | denom[N]
    float* ws = (float*)d_ws;
    float* h     = ws;
    float* e_buf = h + (size_t)N * C;
    float* as    = e_buf + total;
    float* ad    = as + N;
    unsigned int* m_bits = (unsigned int*)(ad + N);
    float* denom = (float*)(m_bits + N);

    const int B = 256;

    node_init_kernel<<<(N + B - 1) / B, B, 0, stream>>>(m_bits, denom, N);
    out_init_kernel<<<(N * C + B - 1) / B, B, 0, stream>>>(out, bias, N * C);

    gemm_alpha_kernel<<<(N + 63) / 64, 256, 0, stream>>>(x, W, a_src, a_dst, h, as, ad, N);

    edge_max_kernel<<<(total + B - 1) / B, B, 0, stream>>>(src, dst, as, ad, e_buf, m_bits, E, total);
    edge_exp_kernel<<<(total + B - 1) / B, B, 0, stream>>>(src, dst, e_buf, m_bits, denom, E, total);

    long long agg_threads = (long long)total * 64;
    int agg_blocks = (int)((agg_threads + B - 1) / B);
    aggregate_kernel<<<agg_blocks, B, 0, stream>>>(src, dst, h, e_buf, denom, out, E, total);

    relu_kernel<<<(N * C + B - 1) / B, B, 0, stream>>>(out, N * C);
}

// Round 2
// 647.528 us; speedup vs baseline: 2.5639x; 2.5639x over previous
//
#include <hip/hip_runtime.h>

#define C 128
#define NEG_SLOPE 0.2f
#define SM_EPS 1e-16f

// ---- init: deg=0 (ws is poisoned 0xAA before every launch) ----
__global__ void deg_init_kernel(int* __restrict__ deg, int N) {
    int i = blockIdx.x * blockDim.x + threadIdx.x;
    if (i < N) deg[i] = 0;
}

// ---- fused GEMM (h = x @ W) + alpha_s/alpha_d reductions ----
__global__ __launch_bounds__(256) void gemm_alpha_kernel(
    const float* __restrict__ x, const float* __restrict__ W,
    const float* __restrict__ a_src, const float* __restrict__ a_dst,
    float* __restrict__ h, float* __restrict__ as_out, float* __restrict__ ad_out,
    int N)
{
    __shared__ float Wl[32 * 128];   // [k][c]
    __shared__ float Xl[32 * 68];    // [k][row], pitch 68

    const int tid  = threadIdx.x;
    const int tcol = tid & 31;
    const int trow = tid >> 5;
    const int row0 = blockIdx.x * 64;

    float acc[8][4];
    #pragma unroll
    for (int r = 0; r < 8; ++r)
        #pragma unroll
        for (int c = 0; c < 4; ++c) acc[r][c] = 0.f;

    for (int kc = 0; kc < 4; ++kc) {
        __syncthreads();
        for (int i = tid; i < 32 * 128; i += 256) {
            int k = i >> 7, c = i & 127;
            Wl[i] = W[(kc * 32 + k) * C + c];
        }
        for (int i = tid; i < 64 * 32; i += 256) {
            int r = i >> 5, k = i & 31;
            int row = row0 + r;
            Xl[k * 68 + r] = (row < N) ? x[(size_t)row * C + kc * 32 + k] : 0.f;
        }
        __syncthreads();

        #pragma unroll
        for (int k = 0; k < 32; ++k) {
            float4 wv = *(const float4*)&Wl[k * 128 + (tcol << 2)];
            float4 x0 = *(const float4*)&Xl[k * 68 + (trow << 3)];
            float4 x1 = *(const float4*)&Xl[k * 68 + (trow << 3) + 4];
            float xr[8] = {x0.x, x0.y, x0.z, x0.w, x1.x, x1.y, x1.z, x1.w};
            #pragma unroll
            for (int r = 0; r < 8; ++r) {
                acc[r][0] += xr[r] * wv.x;
                acc[r][1] += xr[r] * wv.y;
                acc[r][2] += xr[r] * wv.z;
                acc[r][3] += xr[r] * wv.w;
            }
        }
    }

    #pragma unroll
    for (int r = 0; r < 8; ++r) {
        int row = row0 + (trow << 3) + r;
        if (row < N) {
            float4 v = make_float4(acc[r][0], acc[r][1], acc[r][2], acc[r][3]);
            *(float4*)&h[(size_t)row * C + (tcol << 2)] = v;
        }
    }

    float4 asv = *(const float4*)&a_src[tcol << 2];
    float4 adv = *(const float4*)&a_dst[tcol << 2];
    #pragma unroll
    for (int r = 0; r < 8; ++r) {
        float ps = acc[r][0] * asv.x + acc[r][1] * asv.y + acc[r][2] * asv.z + acc[r][3] * asv.w;
        float pd = acc[r][0] * adv.x + acc[r][1] * adv.y + acc[r][2] * adv.z + acc[r][3] * adv.w;
        #pragma unroll
        for (int off = 16; off > 0; off >>= 1) {
            ps += __shfl_down(ps, off, 32);
            pd += __shfl_down(pd, off, 32);
        }
        int row = row0 + (trow << 3) + r;
        if (tcol == 0 && row < N) { as_out[row] = ps; ad_out[row] = pd; }
    }
}

// ---- CSR build step 1: degree count (self-loops appended) ----
__global__ void degree_kernel(const int* __restrict__ dst, int* __restrict__ deg,
                              int E, int total) {
    int i = blockIdx.x * blockDim.x + threadIdx.x;
    if (i >= total) return;
    int d = (i < E) ? dst[i] : (i - E);
    atomicAdd(&deg[d], 1);
}

// ---- CSR build step 2: exclusive scan (single workgroup, wave-shuffle scan) ----
__global__ __launch_bounds__(256) void scan_kernel(const int* __restrict__ deg,
                                                   int* __restrict__ row_start,
                                                   int* __restrict__ cursor, int N) {
    __shared__ int wave_tot[4];
    __shared__ int s_running;
    const int tid  = threadIdx.x;
    const int lane = tid & 63;
    const int wid  = tid >> 6;
    if (tid == 0) s_running = 0;
    __syncthreads();

    for (int base = 0; base < N; base += 256) {
        int i = base + tid;
        int v = (i < N) ? deg[i] : 0;
        // inclusive scan within wave (64 lanes)
        int x = v;
        #pragma unroll
        for (int off = 1; off < 64; off <<= 1) {
            int t = __shfl_up(x, off, 64);
            if (lane >= off) x += t;
        }
        if (lane == 63) wave_tot[wid] = x;
        __syncthreads();
        int wbase = 0;
        #pragma unroll
        for (int w = 0; w < 4; ++w) wbase += (w < wid) ? wave_tot[w] : 0;
        int excl = s_running + wbase + x - v;
        if (i < N) { row_start[i] = excl; cursor[i] = excl; }
        __syncthreads();
        if (tid == 0) s_running += wave_tot[0] + wave_tot[1] + wave_tot[2] + wave_tot[3];
        __syncthreads();
    }
    if (tid == 0) row_start[N] = s_running;
}

// ---- CSR build step 3: bucket scatter of src ids ----
__global__ void scatter_kernel(const int* __restrict__ src, const int* __restrict__ dst,
                               int* __restrict__ cursor, int* __restrict__ csr_src,
                               int E, int total) {
    int i = blockIdx.x * blockDim.x + threadIdx.x;
    if (i >= total) return;
    int s = (i < E) ? src[i] : (i - E);
    int d = (i < E) ? dst[i] : (i - E);
    int pos = atomicAdd(&cursor[d], 1);
    csr_src[pos] = s;
}

// ---- fused softmax + gather-aggregate + bias + relu ----
// one wave per destination node; 2 channels per lane
__global__ __launch_bounds__(256) void gather_kernel(
    const int* __restrict__ csr_src, const int* __restrict__ row_start,
    const float* __restrict__ as, const float* __restrict__ ad,
    const float* __restrict__ h, const float* __restrict__ bias,
    float* __restrict__ out, int N)
{
    const int wid  = threadIdx.x >> 6;
    const int lane = threadIdx.x & 63;
    const int d = blockIdx.x * 4 + wid;
    if (d >= N) return;

    const int beg = row_start[d];
    const int end = row_start[d + 1];
    const float ad_d = ad[d];

    // phase 1: segment max (lanes parallel over edges)
    float m = -INFINITY;
    for (int j = beg + lane; j < end; j += 64) {
        float e = as[csr_src[j]] + ad_d;
        e = (e > 0.f) ? e : NEG_SLOPE * e;
        m = fmaxf(m, e);
    }
    #pragma unroll
    for (int off = 32; off > 0; off >>= 1) m = fmaxf(m, __shfl_xor(m, off, 64));

    // phase 2: sum of exp
    float ssum = 0.f;
    for (int j = beg + lane; j < end; j += 64) {
        float e = as[csr_src[j]] + ad_d;
        e = (e > 0.f) ? e : NEG_SLOPE * e;
        ssum += __expf(e - m);
    }
    #pragma unroll
    for (int off = 32; off > 0; off >>= 1) ssum += __shfl_xor(ssum, off, 64);
    const float inv = 1.f / (ssum + SM_EPS);

    // phase 3: weighted gather, 2 channels per lane (coalesced 512B row reads)
    const int c = lane << 1;
    float acc0 = 0.f, acc1 = 0.f;
    for (int j = beg; j < end; ++j) {
        int s = csr_src[j];
        float e = as[s] + ad_d;                 // broadcast (same addr all lanes)
        e = (e > 0.f) ? e : NEG_SLOPE * e;
        float w = __expf(e - m) * inv;
        float2 hv = *(const float2*)&h[(size_t)s * C + c];
        acc0 += hv.x * w;
        acc1 += hv.y * w;
    }
    float2 b2 = *(const float2*)&bias[c];
    acc0 = fmaxf(acc0 + b2.x, 0.f);
    acc1 = fmaxf(acc1 + b2.y, 0.f);
    *(float2*)&out[(size_t)d * C + c] = make_float2(acc0, acc1);
}

extern "C" void kernel_launch(void* const* d_in, const int* in_sizes, int n_in,
                              void* d_out, int out_size, void* d_ws, size_t ws_size,
                              hipStream_t stream) {
    const float* x     = (const float*)d_in[0];
    const float* W     = (const float*)d_in[1];
    const float* a_src = (const float*)d_in[2];
    const float* a_dst = (const float*)d_in[3];
    const float* bias  = (const float*)d_in[4];
    const int*   edge  = (const int*)d_in[5];

    const int N = in_sizes[0] / C;
    const int E = in_sizes[5] / 2;
    const int total = E + N;                 // edges + self loops
    const int* src = edge;
    const int* dst = edge + E;
    float* out = (float*)d_out;

    // workspace layout (4B elems):
    // h[N*C] | as[N] | ad[N] | deg[N] | row_start[N+1] | cursor[N] | csr_src[total]
    float* ws = (float*)d_ws;
    float* h  = ws;
    float* as = h + (size_t)N * C;
    float* ad = as + N;
    int* deg       = (int*)(ad + N);
    int* row_start = deg + N;
    int* cursor    = row_start + (N + 1);
    int* csr_src   = cursor + N;

    const int B = 256;

    deg_init_kernel<<<(N + B - 1) / B, B, 0, stream>>>(deg, N);
    gemm_alpha_kernel<<<(N + 63) / 64, 256, 0, stream>>>(x, W, a_src, a_dst, h, as, ad, N);
    degree_kernel<<<(total + B - 1) / B, B, 0, stream>>>(dst, deg, E, total);
    scan_kernel<<<1, 256, 0, stream>>>(deg, row_start, cursor, N);
    scatter_kernel<<<(total + B - 1) / B, B, 0, stream>>>(src, dst, cursor, csr_src, E, total);
    gather_kernel<<<(N + 3) / 4, 256, 0, stream>>>(csr_src, row_start, as, ad, h, bias, out, N);
}

// Round 3
// 443.024 us; speedup vs baseline: 3.7474x; 1.4616x over previous
//
#include <hip/hip_runtime.h>

#define C 128
#define NEG_SLOPE 0.2f
#define SM_EPS 1e-16f

typedef unsigned int uint32;
typedef unsigned short ushort16;

// ---- bf16 helpers (RNE) ----
static __device__ __forceinline__ unsigned short f2bf(float f) {
    uint32 u = __float_as_uint(f);
    uint32 r = 0x7FFFu + ((u >> 16) & 1u);
    return (unsigned short)((u + r) >> 16);
}

// ---- init: deg=0 ----
__global__ void deg_init_kernel(int* __restrict__ deg, int N) {
    int i = blockIdx.x * blockDim.x + threadIdx.x;
    if (i < N) deg[i] = 0;
}

// ---- fused GEMM (h = x @ W, stored bf16) + alpha_s/alpha_d reductions ----
__global__ __launch_bounds__(256) void gemm_alpha_kernel(
    const float* __restrict__ x, const float* __restrict__ W,
    const float* __restrict__ a_src, const float* __restrict__ a_dst,
    unsigned short* __restrict__ hb, float* __restrict__ as_out,
    float* __restrict__ ad_out, int N)
{
    __shared__ float Wl[32 * 128];   // [k][c]
    __shared__ float Xl[32 * 68];    // [k][row], pitch 68

    const int tid  = threadIdx.x;
    const int tcol = tid & 31;
    const int trow = tid >> 5;
    const int row0 = blockIdx.x * 64;

    float acc[8][4];
    #pragma unroll
    for (int r = 0; r < 8; ++r)
        #pragma unroll
        for (int c = 0; c < 4; ++c) acc[r][c] = 0.f;

    for (int kc = 0; kc < 4; ++kc) {
        __syncthreads();
        for (int i = tid; i < 32 * 128; i += 256) {
            int k = i >> 7, c = i & 127;
            Wl[i] = W[(kc * 32 + k) * C + c];
        }
        for (int i = tid; i < 64 * 32; i += 256) {
            int r = i >> 5, k = i & 31;
            int row = row0 + r;
            Xl[k * 68 + r] = (row < N) ? x[(size_t)row * C + kc * 32 + k] : 0.f;
        }
        __syncthreads();

        #pragma unroll
        for (int k = 0; k < 32; ++k) {
            float4 wv = *(const float4*)&Wl[k * 128 + (tcol << 2)];
            float4 x0 = *(const float4*)&Xl[k * 68 + (trow << 3)];
            float4 x1 = *(const float4*)&Xl[k * 68 + (trow << 3) + 4];
            float xr[8] = {x0.x, x0.y, x0.z, x0.w, x1.x, x1.y, x1.z, x1.w};
            #pragma unroll
            for (int r = 0; r < 8; ++r) {
                acc[r][0] += xr[r] * wv.x;
                acc[r][1] += xr[r] * wv.y;
                acc[r][2] += xr[r] * wv.z;
                acc[r][3] += xr[r] * wv.w;
            }
        }
    }

    // store h as bf16 (8B per lane, coalesced)
    #pragma unroll
    for (int r = 0; r < 8; ++r) {
        int row = row0 + (trow << 3) + r;
        if (row < N) {
            ushort4 v;
            v.x = f2bf(acc[r][0]); v.y = f2bf(acc[r][1]);
            v.z = f2bf(acc[r][2]); v.w = f2bf(acc[r][3]);
            *(ushort4*)&hb[(size_t)row * C + (tcol << 2)] = v;
        }
    }

    float4 asv = *(const float4*)&a_src[tcol << 2];
    float4 adv = *(const float4*)&a_dst[tcol << 2];
    #pragma unroll
    for (int r = 0; r < 8; ++r) {
        float ps = acc[r][0] * asv.x + acc[r][1] * asv.y + acc[r][2] * asv.z + acc[r][3] * asv.w;
        float pd = acc[r][0] * adv.x + acc[r][1] * adv.y + acc[r][2] * adv.z + acc[r][3] * adv.w;
        #pragma unroll
        for (int off = 16; off > 0; off >>= 1) {
            ps += __shfl_down(ps, off, 32);
            pd += __shfl_down(pd, off, 32);
        }
        int row = row0 + (trow << 3) + r;
        if (tcol == 0 && row < N) { as_out[row] = ps; ad_out[row] = pd; }
    }
}

// ---- CSR build step 1: degree count ----
__global__ void degree_kernel(const int* __restrict__ dst, int* __restrict__ deg,
                              int E, int total) {
    int i = blockIdx.x * blockDim.x + threadIdx.x;
    if (i >= total) return;
    int d = (i < E) ? dst[i] : (i - E);
    atomicAdd(&deg[d], 1);
}

// ---- CSR build step 2a: per-block exclusive scan + block sums ----
__global__ __launch_bounds__(256) void scan_block_kernel(
    const int* __restrict__ deg, int* __restrict__ partial,
    int* __restrict__ block_sum, int N)
{
    __shared__ int wave_tot[4];
    const int tid = threadIdx.x, lane = tid & 63, wid = tid >> 6;
    const int i = blockIdx.x * 256 + tid;
    int v = (i < N) ? deg[i] : 0;
    int x = v;
    #pragma unroll
    for (int off = 1; off < 64; off <<= 1) {
        int t = __shfl_up(x, off, 64);
        if (lane >= off) x += t;
    }
    if (lane == 63) wave_tot[wid] = x;
    __syncthreads();
    int wbase = 0;
    #pragma unroll
    for (int w = 0; w < 4; ++w) wbase += (w < wid) ? wave_tot[w] : 0;
    if (i < N) partial[i] = wbase + x - v;
    if (tid == 255) block_sum[blockIdx.x] = wbase + x;
}

// ---- CSR build step 2b: exclusive scan of block sums (nb <= 256) ----
__global__ __launch_bounds__(256) void scan_sums_kernel(int* __restrict__ block_sum, int nb) {
    __shared__ int wave_tot[4];
    const int tid = threadIdx.x, lane = tid & 63, wid = tid >> 6;
    int v = (tid < nb) ? block_sum[tid] : 0;
    int x = v;
    #pragma unroll
    for (int off = 1; off < 64; off <<= 1) {
        int t = __shfl_up(x, off, 64);
        if (lane >= off) x += t;
    }
    if (lane == 63) wave_tot[wid] = x;
    __syncthreads();
    int wbase = 0;
    #pragma unroll
    for (int w = 0; w < 4; ++w) wbase += (w < wid) ? wave_tot[w] : 0;
    if (tid < nb) block_sum[tid] = wbase + x - v;
}

// ---- CSR build step 2c: finalize row_start / cursor ----
__global__ __launch_bounds__(256) void scan_final_kernel(
    const int* __restrict__ partial, const int* __restrict__ block_sum,
    int* __restrict__ row_start, int* __restrict__ cursor, int N, int total)
{
    const int i = blockIdx.x * 256 + threadIdx.x;
    if (i < N) {
        int v = partial[i] + block_sum[blockIdx.x];
        row_start[i] = v;
        cursor[i] = v;
    }
    if (i == 0) row_start[N] = total;
}

// ---- CSR build step 3: bucket scatter of src ids ----
__global__ void scatter_kernel(const int* __restrict__ src, const int* __restrict__ dst,
                               int* __restrict__ cursor, int* __restrict__ csr_src,
                               int E, int total) {
    int i = blockIdx.x * blockDim.x + threadIdx.x;
    if (i >= total) return;
    int s = (i < E) ? src[i] : (i - E);
    int d = (i < E) ? dst[i] : (i - E);
    int pos = atomicAdd(&cursor[d], 1);
    csr_src[pos] = s;
}

// ---- fused softmax + gather-aggregate + bias + relu ----
// one wave per destination node; 2 channels per lane; h in bf16
__global__ __launch_bounds__(256) void gather_kernel(
    const int* __restrict__ csr_src, const int* __restrict__ row_start,
    const float* __restrict__ as, const float* __restrict__ ad,
    const unsigned short* __restrict__ hb, const float* __restrict__ bias,
    float* __restrict__ out, int N)
{
    const int wid  = threadIdx.x >> 6;
    const int lane = threadIdx.x & 63;
    const int d = blockIdx.x * 4 + wid;
    if (d >= N) return;

    const int beg = row_start[d];
    const int end = row_start[d + 1];
    const float ad_d = ad[d];

    // phase 1: segment max
    float m = -INFINITY;
    for (int j = beg + lane; j < end; j += 64) {
        float e = as[csr_src[j]] + ad_d;
        e = (e > 0.f) ? e : NEG_SLOPE * e;
        m = fmaxf(m, e);
    }
    #pragma unroll
    for (int off = 32; off > 0; off >>= 1) m = fmaxf(m, __shfl_xor(m, off, 64));

    // phase 2: sum of exp
    float ssum = 0.f;
    for (int j = beg + lane; j < end; j += 64) {
        float e = as[csr_src[j]] + ad_d;
        e = (e > 0.f) ? e : NEG_SLOPE * e;
        ssum += __expf(e - m);
    }
    #pragma unroll
    for (int off = 32; off > 0; off >>= 1) ssum += __shfl_xor(ssum, off, 64);
    const float inv = 1.f / (ssum + SM_EPS);

    // phase 3: weighted gather, 2 bf16 channels per lane, unrolled x2
    const int c = lane << 1;
    float acc0 = 0.f, acc1 = 0.f;
    int j = beg;
    for (; j + 2 <= end; j += 2) {
        int s0 = csr_src[j], s1 = csr_src[j + 1];
        float e0 = as[s0] + ad_d; e0 = (e0 > 0.f) ? e0 : NEG_SLOPE * e0;
        float e1 = as[s1] + ad_d; e1 = (e1 > 0.f) ? e1 : NEG_SLOPE * e1;
        uint32 u0 = *(const uint32*)&hb[(size_t)s0 * C + c];
        uint32 u1 = *(const uint32*)&hb[(size_t)s1 * C + c];
        float w0 = __expf(e0 - m) * inv;
        float w1 = __expf(e1 - m) * inv;
        acc0 += __uint_as_float(u0 << 16) * w0 + __uint_as_float(u1 << 16) * w1;
        acc1 += __uint_as_float(u0 & 0xffff0000u) * w0 + __uint_as_float(u1 & 0xffff0000u) * w1;
    }
    if (j < end) {
        int s0 = csr_src[j];
        float e0 = as[s0] + ad_d; e0 = (e0 > 0.f) ? e0 : NEG_SLOPE * e0;
        uint32 u0 = *(const uint32*)&hb[(size_t)s0 * C + c];
        float w0 = __expf(e0 - m) * inv;
        acc0 += __uint_as_float(u0 << 16) * w0;
        acc1 += __uint_as_float(u0 & 0xffff0000u) * w0;
    }
    float2 b2 = *(const float2*)&bias[c];
    acc0 = fmaxf(acc0 + b2.x, 0.f);
    acc1 = fmaxf(acc1 + b2.y, 0.f);
    *(float2*)&out[(size_t)d * C + c] = make_float2(acc0, acc1);
}

extern "C" void kernel_launch(void* const* d_in, const int* in_sizes, int n_in,
                              void* d_out, int out_size, void* d_ws, size_t ws_size,
                              hipStream_t stream) {
    const float* x     = (const float*)d_in[0];
    const float* W     = (const float*)d_in[1];
    const float* a_src = (const float*)d_in[2];
    const float* a_dst = (const float*)d_in[3];
    const float* bias  = (const float*)d_in[4];
    const int*   edge  = (const int*)d_in[5];

    const int N = in_sizes[0] / C;
    const int E = in_sizes[5] / 2;
    const int total = E + N;
    const int* src = edge;
    const int* dst = edge + E;
    float* out = (float*)d_out;

    const int B = 256;
    const int nb = (N + B - 1) / B;   // scan blocks (<=256 required; 196 here)

    // workspace layout (4B units):
    // hb[N*C/2 uints] | as[N] | ad[N] | deg[N] | partial[N] | row_start[N+1] |
    // cursor[N] | block_sum[nb] | csr_src[total]
    float* ws = (float*)d_ws;
    unsigned short* hb = (unsigned short*)ws;
    float* as = (float*)(hb + (size_t)N * C);
    float* ad = as + N;
    int* deg       = (int*)(ad + N);
    int* partial   = deg + N;
    int* row_start = partial + N;
    int* cursor    = row_start + (N + 1);
    int* block_sum = cursor + N;
    int* csr_src   = block_sum + nb;

    deg_init_kernel<<<(N + B - 1) / B, B, 0, stream>>>(deg, N);
    gemm_alpha_kernel<<<(N + 63) / 64, 256, 0, stream>>>(x, W, a_src, a_dst, hb, as, ad, N);
    degree_kernel<<<(total + B - 1) / B, B, 0, stream>>>(dst, deg, E, total);
    scan_block_kernel<<<nb, B, 0, stream>>>(deg, partial, block_sum, N);
    scan_sums_kernel<<<1, B, 0, stream>>>(block_sum, nb);
    scan_final_kernel<<<nb, B, 0, stream>>>(partial, block_sum, row_start, cursor, N, total);
    scatter_kernel<<<(total + B - 1) / B, B, 0, stream>>>(src, dst, cursor, csr_src, E, total);
    gather_kernel<<<(N + 3) / 4, 256, 0, stream>>>(csr_src, row_start, as, ad, hb, bias, out, N);
}

// Round 4
// 319.293 us; speedup vs baseline: 5.1996x; 1.3875x over previous
//
#include <hip/hip_runtime.h>

#define C 128
#define NEG_SLOPE 0.2f
#define SM_EPS 1e-16f
#define BKT_SHIFT 8                    // 256 nodes per bucket
#define BKT_MASK 255
#define BIN_CHUNK 8192

typedef unsigned int uint32;

// ---- bf16 helpers (RNE) ----
static __device__ __forceinline__ unsigned short f2bf(float f) {
    uint32 u = __float_as_uint(f);
    uint32 r = 0x7FFFu + ((u >> 16) & 1u);
    return (unsigned short)((u + r) >> 16);
}

// ---- fused GEMM (h = x @ W, stored bf16) + alpha_s/alpha_d reductions ----
__global__ __launch_bounds__(256) void gemm_alpha_kernel(
    const float* __restrict__ x, const float* __restrict__ W,
    const float* __restrict__ a_src, const float* __restrict__ a_dst,
    unsigned short* __restrict__ hb, float* __restrict__ as_out,
    float* __restrict__ ad_out, int N)
{
    __shared__ float Wl[32 * 128];
    __shared__ float Xl[32 * 68];

    const int tid  = threadIdx.x;
    const int tcol = tid & 31;
    const int trow = tid >> 5;
    const int row0 = blockIdx.x * 64;

    float acc[8][4];
    #pragma unroll
    for (int r = 0; r < 8; ++r)
        #pragma unroll
        for (int c = 0; c < 4; ++c) acc[r][c] = 0.f;

    for (int kc = 0; kc < 4; ++kc) {
        __syncthreads();
        for (int i = tid; i < 32 * 128; i += 256) {
            int k = i >> 7, c = i & 127;
            Wl[i] = W[(kc * 32 + k) * C + c];
        }
        for (int i = tid; i < 64 * 32; i += 256) {
            int r = i >> 5, k = i & 31;
            int row = row0 + r;
            Xl[k * 68 + r] = (row < N) ? x[(size_t)row * C + kc * 32 + k] : 0.f;
        }
        __syncthreads();

        #pragma unroll
        for (int k = 0; k < 32; ++k) {
            float4 wv = *(const float4*)&Wl[k * 128 + (tcol << 2)];
            float4 x0 = *(const float4*)&Xl[k * 68 + (trow << 3)];
            float4 x1 = *(const float4*)&Xl[k * 68 + (trow << 3) + 4];
            float xr[8] = {x0.x, x0.y, x0.z, x0.w, x1.x, x1.y, x1.z, x1.w};
            #pragma unroll
            for (int r = 0; r < 8; ++r) {
                acc[r][0] += xr[r] * wv.x;
                acc[r][1] += xr[r] * wv.y;
                acc[r][2] += xr[r] * wv.z;
                acc[r][3] += xr[r] * wv.w;
            }
        }
    }

    #pragma unroll
    for (int r = 0; r < 8; ++r) {
        int row = row0 + (trow << 3) + r;
        if (row < N) {
            ushort4 v;
            v.x = f2bf(acc[r][0]); v.y = f2bf(acc[r][1]);
            v.z = f2bf(acc[r][2]); v.w = f2bf(acc[r][3]);
            *(ushort4*)&hb[(size_t)row * C + (tcol << 2)] = v;
        }
    }

    float4 asv = *(const float4*)&a_src[tcol << 2];
    float4 adv = *(const float4*)&a_dst[tcol << 2];
    #pragma unroll
    for (int r = 0; r < 8; ++r) {
        float ps = acc[r][0] * asv.x + acc[r][1] * asv.y + acc[r][2] * asv.z + acc[r][3] * asv.w;
        float pd = acc[r][0] * adv.x + acc[r][1] * adv.y + acc[r][2] * adv.z + acc[r][3] * adv.w;
        #pragma unroll
        for (int off = 16; off > 0; off >>= 1) {
            ps += __shfl_down(ps, off, 32);
            pd += __shfl_down(pd, off, 32);
        }
        int row = row0 + (trow << 3) + r;
        if (tcol == 0 && row < N) { as_out[row] = ps; ad_out[row] = pd; }
    }
}

// ---- zero small int buffer ----
__global__ void zero_kernel(int* __restrict__ p, int n) {
    int i = blockIdx.x * blockDim.x + threadIdx.x;
    if (i < n) p[i] = 0;
}

// ---- binning step 1: bucket histogram (LDS-aggregated) ----
__global__ __launch_bounds__(256) void hist_kernel(
    const int* __restrict__ dst, int* __restrict__ bucket_cnt,
    int E, int total, int NB)
{
    __shared__ int hist[256];
    const int tid = threadIdx.x;
    hist[tid] = 0;
    __syncthreads();
    for (int i = blockIdx.x * 256 + tid; i < total; i += gridDim.x * 256) {
        int d = (i < E) ? dst[i] : (i - E);
        atomicAdd(&hist[d >> BKT_SHIFT], 1);
    }
    __syncthreads();
    if (tid < NB && hist[tid]) atomicAdd(&bucket_cnt[tid], hist[tid]);
}

// ---- binning step 2: exclusive scan of bucket counts (NB <= 256) ----
__global__ __launch_bounds__(256) void scan_off_kernel(
    const int* __restrict__ bucket_cnt, int* __restrict__ bucket_off,
    int* __restrict__ bucket_cursor, int* __restrict__ row_start,
    int NB, int N, int total)
{
    __shared__ int wave_tot[4];
    const int tid = threadIdx.x, lane = tid & 63, wid = tid >> 6;
    int v = (tid < NB) ? bucket_cnt[tid] : 0;
    int x = v;
    #pragma unroll
    for (int off = 1; off < 64; off <<= 1) {
        int t = __shfl_up(x, off, 64);
        if (lane >= off) x += t;
    }
    if (lane == 63) wave_tot[wid] = x;
    __syncthreads();
    int wbase = 0;
    #pragma unroll
    for (int w = 0; w < 4; ++w) wbase += (w < wid) ? wave_tot[w] : 0;
    int excl = wbase + x - v;
    if (tid < NB) { bucket_off[tid] = excl; bucket_cursor[tid] = excl; }
    if (tid == 0) { bucket_off[NB] = total; row_start[N] = total; }
}

// ---- binning step 3: scatter edges into bucket-contiguous packed runs ----
// packed = (src << 8) | (dst & 255); runs per (block,bucket) are contiguous.
__global__ __launch_bounds__(256) void bin_kernel(
    const int* __restrict__ src, const int* __restrict__ dst,
    int* __restrict__ bucket_cursor, uint32* __restrict__ packed,
    int E, int total, int NB)
{
    __shared__ int hist[256];
    __shared__ int base[256];
    const int tid = threadIdx.x;
    const int start = blockIdx.x * BIN_CHUNK;
    const int end = min(start + BIN_CHUNK, total);

    hist[tid] = 0;
    __syncthreads();
    for (int i = start + tid; i < end; i += 256) {
        int d = (i < E) ? dst[i] : (i - E);
        atomicAdd(&hist[d >> BKT_SHIFT], 1);
    }
    __syncthreads();
    if (tid < NB) {
        int c = hist[tid];
        base[tid] = c ? atomicAdd(&bucket_cursor[tid], c) : 0;
    }
    hist[tid] = 0;                 // reuse as per-block bucket cursor
    __syncthreads();
    for (int i = start + tid; i < end; i += 256) {
        int s = (i < E) ? src[i] : (i - E);
        int d = (i < E) ? dst[i] : (i - E);
        int b = d >> BKT_SHIFT;
        int pos = base[b] + atomicAdd(&hist[b], 1);
        packed[pos] = ((uint32)s << BKT_SHIFT) | (uint32)(d & BKT_MASK);
    }
}

// ---- binning step 4: per-bucket fine counting sort (LDS) + row_start ----
__global__ __launch_bounds__(256) void build_kernel(
    const uint32* __restrict__ packed, const int* __restrict__ bucket_off,
    int* __restrict__ row_start, int* __restrict__ csr_src, int N)
{
    __shared__ int cnt[256];
    __shared__ int cur[256];
    __shared__ int wave_tot[4];
    const int tid = threadIdx.x, lane = tid & 63, wid = tid >> 6;
    const int b = blockIdx.x;
    const int off = bucket_off[b];
    const int end = bucket_off[b + 1];

    cnt[tid] = 0;
    __syncthreads();
    for (int j = off + tid; j < end; j += 256)
        atomicAdd(&cnt[packed[j] & BKT_MASK], 1);
    __syncthreads();

    int v = cnt[tid], x = v;
    #pragma unroll
    for (int o = 1; o < 64; o <<= 1) {
        int t = __shfl_up(x, o, 64);
        if (lane >= o) x += t;
    }
    if (lane == 63) wave_tot[wid] = x;
    __syncthreads();
    int wbase = 0;
    #pragma unroll
    for (int w = 0; w < 4; ++w) wbase += (w < wid) ? wave_tot[w] : 0;
    int excl = wbase + x - v;

    int g = (b << BKT_SHIFT) + tid;
    if (g < N) row_start[g] = off + excl;
    cur[tid] = excl;
    __syncthreads();

    for (int j = off + tid; j < end; j += 256) {
        uint32 p = packed[j];
        int l = p & BKT_MASK;
        int pos = atomicAdd(&cur[l], 1);
        csr_src[off + pos] = (int)(p >> BKT_SHIFT);
    }
}

// ---- fused softmax + gather-aggregate + bias + relu ----
__global__ __launch_bounds__(256) void gather_kernel(
    const int* __restrict__ csr_src, const int* __restrict__ row_start,
    const float* __restrict__ as, const float* __restrict__ ad,
    const unsigned short* __restrict__ hb, const float* __restrict__ bias,
    float* __restrict__ out, int N)
{
    const int wid  = threadIdx.x >> 6;
    const int lane = threadIdx.x & 63;
    const int d = blockIdx.x * 4 + wid;
    if (d >= N) return;

    const int beg = row_start[d];
    const int end = row_start[d + 1];
    const float ad_d = ad[d];

    float m = -INFINITY;
    for (int j = beg + lane; j < end; j += 64) {
        float e = as[csr_src[j]] + ad_d;
        e = (e > 0.f) ? e : NEG_SLOPE * e;
        m = fmaxf(m, e);
    }
    #pragma unroll
    for (int off = 32; off > 0; off >>= 1) m = fmaxf(m, __shfl_xor(m, off, 64));

    float ssum = 0.f;
    for (int j = beg + lane; j < end; j += 64) {
        float e = as[csr_src[j]] + ad_d;
        e = (e > 0.f) ? e : NEG_SLOPE * e;
        ssum += __expf(e - m);
    }
    #pragma unroll
    for (int off = 32; off > 0; off >>= 1) ssum += __shfl_xor(ssum, off, 64);
    const float inv = 1.f / (ssum + SM_EPS);

    const int c = lane << 1;
    float acc0 = 0.f, acc1 = 0.f;
    int j = beg;
    for (; j + 2 <= end; j += 2) {
        int s0 = csr_src[j], s1 = csr_src[j + 1];
        float e0 = as[s0] + ad_d; e0 = (e0 > 0.f) ? e0 : NEG_SLOPE * e0;
        float e1 = as[s1] + ad_d; e1 = (e1 > 0.f) ? e1 : NEG_SLOPE * e1;
        uint32 u0 = *(const uint32*)&hb[(size_t)s0 * C + c];
        uint32 u1 = *(const uint32*)&hb[(size_t)s1 * C + c];
        float w0 = __expf(e0 - m) * inv;
        float w1 = __expf(e1 - m) * inv;
        acc0 += __uint_as_float(u0 << 16) * w0 + __uint_as_float(u1 << 16) * w1;
        acc1 += __uint_as_float(u0 & 0xffff0000u) * w0 + __uint_as_float(u1 & 0xffff0000u) * w1;
    }
    if (j < end) {
        int s0 = csr_src[j];
        float e0 = as[s0] + ad_d; e0 = (e0 > 0.f) ? e0 : NEG_SLOPE * e0;
        uint32 u0 = *(const uint32*)&hb[(size_t)s0 * C + c];
        float w0 = __expf(e0 - m) * inv;
        acc0 += __uint_as_float(u0 << 16) * w0;
        acc1 += __uint_as_float(u0 & 0xffff0000u) * w0;
    }
    float2 b2 = *(const float2*)&bias[c];
    acc0 = fmaxf(acc0 + b2.x, 0.f);
    acc1 = fmaxf(acc1 + b2.y, 0.f);
    *(float2*)&out[(size_t)d * C + c] = make_float2(acc0, acc1);
}

extern "C" void kernel_launch(void* const* d_in, const int* in_sizes, int n_in,
                              void* d_out, int out_size, void* d_ws, size_t ws_size,
                              hipStream_t stream) {
    const float* x     = (const float*)d_in[0];
    const float* W     = (const float*)d_in[1];
    const float* a_src = (const float*)d_in[2];
    const float* a_dst = (const float*)d_in[3];
    const float* bias  = (const float*)d_in[4];
    const int*   edge  = (const int*)d_in[5];

    const int N = in_sizes[0] / C;
    const int E = in_sizes[5] / 2;
    const int total = E + N;
    const int* src = edge;
    const int* dst = edge + E;
    float* out = (float*)d_out;

    const int NB = (N + BKT_MASK) >> BKT_SHIFT;   // 196 buckets (<=256 required)

    // workspace (4B units):
    // hb[N*C/2] | as[N] | ad[N] | row_start[N+1] | packed[total] | csr_src[total]
    // | bucket_cnt[NB] | bucket_off[NB+1] | bucket_cursor[NB]
    float* ws = (float*)d_ws;
    unsigned short* hb = (unsigned short*)ws;
    float* as = (float*)(hb + (size_t)N * C);
    float* ad = as + N;
    int* row_start     = (int*)(ad + N);
    uint32* packed     = (uint32*)(row_start + (N + 1));
    int* csr_src       = (int*)(packed + total);
    int* bucket_cnt    = csr_src + total;
    int* bucket_off    = bucket_cnt + NB;
    int* bucket_cursor = bucket_off + (NB + 1);

    zero_kernel<<<(NB + 255) / 256, 256, 0, stream>>>(bucket_cnt, NB);
    gemm_alpha_kernel<<<(N + 63) / 64, 256, 0, stream>>>(x, W, a_src, a_dst, hb, as, ad, N);
    hist_kernel<<<256, 256, 0, stream>>>(dst, bucket_cnt, E, total, NB);
    scan_off_kernel<<<1, 256, 0, stream>>>(bucket_cnt, bucket_off, bucket_cursor,
                                           row_start, NB, N, total);
    bin_kernel<<<(total + BIN_CHUNK - 1) / BIN_CHUNK, 256, 0, stream>>>(
        src, dst, bucket_cursor, packed, E, total, NB);
    build_kernel<<<NB, 256, 0, stream>>>(packed, bucket_off, row_start, csr_src, N);
    gather_kernel<<<(N + 3) / 4, 256, 0, stream>>>(csr_src, row_start, as, ad, hb, bias, out, N);
}

// Round 5
// 232.952 us; speedup vs baseline: 7.1268x; 1.3706x over previous
//
#include <hip/hip_runtime.h>

#define C 128
#define NEG_SLOPE 0.2f
#define SM_EPS 1e-16f
#define BKT_SHIFT 8
#define BKT_MASK 255
#define BIN_CHUNK 8192
#define CAP 128            // per-wave cached edges (max degree here ~65)
#define WP 136             // LDS pitch in u16 units (272 B: 16B-aligned, even bank groups)

typedef unsigned int uint32;
typedef __attribute__((ext_vector_type(8))) short bf16x8;
typedef __attribute__((ext_vector_type(4))) float f32x4;

// ---- bf16 helpers (RNE) ----
static __device__ __forceinline__ unsigned short f2bf(float f) {
    uint32 u = __float_as_uint(f);
    uint32 r = 0x7FFFu + ((u >> 16) & 1u);
    return (unsigned short)((u + r) >> 16);
}
static __device__ __forceinline__ uint32 f2bf2(float lo, float hi) {
    return (uint32)f2bf(lo) | ((uint32)f2bf(hi) << 16);
}

// ---- MFMA bf16 GEMM (h = x @ W) + alpha_s/alpha_d + bf16 h store ----
// block = 256 thr = 4 waves; tile 64 rows x 128 cols; wave w owns rows 16w..16w+15.
__global__ __launch_bounds__(256) void gemm_mfma_kernel(
    const float* __restrict__ x, const float* __restrict__ W,
    const float* __restrict__ a_src, const float* __restrict__ a_dst,
    unsigned short* __restrict__ hb, float* __restrict__ as_out,
    float* __restrict__ ad_out, int N)
{
    __shared__ __align__(16) unsigned short Wl[128 * WP];  // W^T bf16: [n][k]
    __shared__ __align__(16) unsigned short Xl[64 * WP];   // x bf16:  [r][k]

    const int tid  = threadIdx.x;
    const int lane = tid & 63;
    const int w    = tid >> 6;
    const int row0 = blockIdx.x * 64;

    // stage W^T (bf16), one k-pair per thread-iter
    for (int i = tid; i < 64 * 128; i += 256) {
        int n = i & 127, kp = i >> 7;                  // kp = k/2
        float w0 = W[(2 * kp) * C + n];
        float w1 = W[(2 * kp + 1) * C + n];
        *(uint32*)&Wl[n * WP + 2 * kp] = f2bf2(w0, w1);
    }
    // stage x (bf16), coalesced float2 reads
    for (int i = tid; i < 64 * 64; i += 256) {
        int r = i >> 6, kp = i & 63;
        int row = row0 + r;
        float2 xv = (row < N) ? *(const float2*)&x[(size_t)row * C + 2 * kp]
                              : make_float2(0.f, 0.f);
        *(uint32*)&Xl[r * WP + 2 * kp] = f2bf2(xv.x, xv.y);
    }
    __syncthreads();

    const int m16 = lane & 15;        // col-in-tile / row-in-tile for A
    const int q   = lane >> 4;        // quad 0..3

    f32x4 acc[8];
    const f32x4 zz = {0.f, 0.f, 0.f, 0.f};
    #pragma unroll
    for (int t = 0; t < 8; ++t) acc[t] = zz;

    #pragma unroll
    for (int kk = 0; kk < 4; ++kk) {
        const int k0 = kk * 32 + q * 8;
        bf16x8 a = *(const bf16x8*)&Xl[(w * 16 + m16) * WP + k0];
        #pragma unroll
        for (int t = 0; t < 8; ++t) {
            bf16x8 b = *(const bf16x8*)&Wl[(t * 16 + m16) * WP + k0];
            acc[t] = __builtin_amdgcn_mfma_f32_16x16x32_bf16(a, b, acc[t], 0, 0, 0);
        }
    }

    // alpha reductions from fp32 accumulators
    // C/D layout (m89-verified): col = t*16 + m16, row = q*4 + reg
    float ps[4] = {0.f, 0.f, 0.f, 0.f}, pd[4] = {0.f, 0.f, 0.f, 0.f};
    #pragma unroll
    for (int t = 0; t < 8; ++t) {
        float av = a_src[t * 16 + m16];
        float dv = a_dst[t * 16 + m16];
        #pragma unroll
        for (int r = 0; r < 4; ++r) {
            ps[r] += acc[t][r] * av;
            pd[r] += acc[t][r] * dv;
        }
    }
    #pragma unroll
    for (int r = 0; r < 4; ++r) {
        #pragma unroll
        for (int off = 1; off < 16; off <<= 1) {
            ps[r] += __shfl_xor(ps[r], off, 64);
            pd[r] += __shfl_xor(pd[r], off, 64);
        }
    }
    if (m16 == 0) {
        #pragma unroll
        for (int r = 0; r < 4; ++r) {
            int row = row0 + w * 16 + q * 4 + r;
            if (row < N) { as_out[row] = ps[r]; ad_out[row] = pd[r]; }
        }
    }

    // h writeback: layout-transform through this wave's own Xl slice
    unsigned short* slice = &Xl[w * 16 * WP];
    #pragma unroll
    for (int t = 0; t < 8; ++t)
        #pragma unroll
        for (int r = 0; r < 4; ++r)
            slice[(q * 4 + r) * WP + t * 16 + m16] = f2bf(acc[t][r]);
    __syncthreads();   // order LDS writes vs cross-lane reads (all threads reach)
    #pragma unroll
    for (int it = 0; it < 4; ++it) {
        int r = it * 4 + q;
        int row = row0 + w * 16 + r;
        if (row < N) {
            bf16x8 v = *(const bf16x8*)&slice[r * WP + m16 * 8];
            *(bf16x8*)&hb[(size_t)row * C + m16 * 8] = v;
        }
    }
}

// ---- zero small int buffer ----
__global__ void zero_kernel(int* __restrict__ p, int n) {
    int i = blockIdx.x * blockDim.x + threadIdx.x;
    if (i < n) p[i] = 0;
}

// ---- binning step 1: bucket histogram ----
__global__ __launch_bounds__(256) void hist_kernel(
    const int* __restrict__ dst, int* __restrict__ bucket_cnt,
    int E, int total, int NB)
{
    __shared__ int hist[256];
    const int tid = threadIdx.x;
    hist[tid] = 0;
    __syncthreads();
    for (int i = blockIdx.x * 256 + tid; i < total; i += gridDim.x * 256) {
        int d = (i < E) ? dst[i] : (i - E);
        atomicAdd(&hist[d >> BKT_SHIFT], 1);
    }
    __syncthreads();
    if (tid < NB && hist[tid]) atomicAdd(&bucket_cnt[tid], hist[tid]);
}

// ---- binning step 2: scan of bucket counts ----
__global__ __launch_bounds__(256) void scan_off_kernel(
    const int* __restrict__ bucket_cnt, int* __restrict__ bucket_off,
    int* __restrict__ bucket_cursor, int* __restrict__ row_start,
    int NB, int N, int total)
{
    __shared__ int wave_tot[4];
    const int tid = threadIdx.x, lane = tid & 63, wid = tid >> 6;
    int v = (tid < NB) ? bucket_cnt[tid] : 0;
    int x = v;
    #pragma unroll
    for (int off = 1; off < 64; off <<= 1) {
        int t = __shfl_up(x, off, 64);
        if (lane >= off) x += t;
    }
    if (lane == 63) wave_tot[wid] = x;
    __syncthreads();
    int wbase = 0;
    #pragma unroll
    for (int w = 0; w < 4; ++w) wbase += (w < wid) ? wave_tot[w] : 0;
    int excl = wbase + x - v;
    if (tid < NB) { bucket_off[tid] = excl; bucket_cursor[tid] = excl; }
    if (tid == 0) { bucket_off[NB] = total; row_start[N] = total; }
}

// ---- binning step 3: scatter into bucket-contiguous packed runs ----
__global__ __launch_bounds__(256) void bin_kernel(
    const int* __restrict__ src, const int* __restrict__ dst,
    int* __restrict__ bucket_cursor, uint32* __restrict__ packed,
    int E, int total, int NB)
{
    __shared__ int hist[256];
    __shared__ int base[256];
    const int tid = threadIdx.x;
    const int start = blockIdx.x * BIN_CHUNK;
    const int end = min(start + BIN_CHUNK, total);

    hist[tid] = 0;
    __syncthreads();
    for (int i = start + tid; i < end; i += 256) {
        int d = (i < E) ? dst[i] : (i - E);
        atomicAdd(&hist[d >> BKT_SHIFT], 1);
    }
    __syncthreads();
    if (tid < NB) {
        int c = hist[tid];
        base[tid] = c ? atomicAdd(&bucket_cursor[tid], c) : 0;
    }
    hist[tid] = 0;
    __syncthreads();
    for (int i = start + tid; i < end; i += 256) {
        int s = (i < E) ? src[i] : (i - E);
        int d = (i < E) ? dst[i] : (i - E);
        int b = d >> BKT_SHIFT;
        int pos = base[b] + atomicAdd(&hist[b], 1);
        packed[pos] = ((uint32)s << BKT_SHIFT) | (uint32)(d & BKT_MASK);
    }
}

// ---- binning step 4: per-bucket fine counting sort ----
__global__ __launch_bounds__(256) void build_kernel(
    const uint32* __restrict__ packed, const int* __restrict__ bucket_off,
    int* __restrict__ row_start, int* __restrict__ csr_src, int N)
{
    __shared__ int cnt[256];
    __shared__ int cur[256];
    __shared__ int wave_tot[4];
    const int tid = threadIdx.x, lane = tid & 63, wid = tid >> 6;
    const int b = blockIdx.x;
    const int off = bucket_off[b];
    const int end = bucket_off[b + 1];

    cnt[tid] = 0;
    __syncthreads();
    for (int j = off + tid; j < end; j += 256)
        atomicAdd(&cnt[packed[j] & BKT_MASK], 1);
    __syncthreads();

    int v = cnt[tid], x = v;
    #pragma unroll
    for (int o = 1; o < 64; o <<= 1) {
        int t = __shfl_up(x, o, 64);
        if (lane >= o) x += t;
    }
    if (lane == 63) wave_tot[wid] = x;
    __syncthreads();
    int wbase = 0;
    #pragma unroll
    for (int w = 0; w < 4; ++w) wbase += (w < wid) ? wave_tot[w] : 0;
    int excl = wbase + x - v;

    int g = (b << BKT_SHIFT) + tid;
    if (g < N) row_start[g] = off + excl;
    cur[tid] = excl;
    __syncthreads();

    for (int j = off + tid; j < end; j += 256) {
        uint32 p = packed[j];
        int l = p & BKT_MASK;
        int pos = atomicAdd(&cur[l], 1);
        csr_src[off + pos] = (int)(p >> BKT_SHIFT);
    }
}

// ---- fused softmax + gather-aggregate + bias + relu ----
// one wave per dst node; per-edge (src, weight) cached in LDS
__global__ __launch_bounds__(256) void gather_kernel(
    const int* __restrict__ csr_src, const int* __restrict__ row_start,
    const float* __restrict__ as, const float* __restrict__ ad,
    const unsigned short* __restrict__ hb, const float* __restrict__ bias,
    float* __restrict__ out, int N)
{
    __shared__ uint2 cache[4][CAP];
    const int w    = threadIdx.x >> 6;
    const int lane = threadIdx.x & 63;
    const int d = blockIdx.x * 4 + w;
    const bool active = (d < N);

    int beg = 0, deg = 0;
    float ad_d = 0.f, m = -INFINITY, ssum = 0.f, inv = 0.f;
    bool small = true;

    if (active) {
        beg = row_start[d];
        deg = row_start[d + 1] - beg;
        ad_d = ad[d];
        small = (deg <= CAP);

        if (small) {
            // pass 1: gather src + e, cache, per-lane online max/sum
            for (int t = lane; t < deg; t += 64) {
                int s = csr_src[beg + t];
                float e = as[s] + ad_d;
                e = (e > 0.f) ? e : NEG_SLOPE * e;
                cache[w][t] = make_uint2((uint32)s, __float_as_uint(e));
                float nm = fmaxf(m, e);
                ssum = ssum * ((m == nm) ? 1.f : __expf(m - nm)) + __expf(e - nm);
                m = nm;
            }
        } else {
            // fallback: two-pass max + sum (recompute)
            for (int t = lane; t < deg; t += 64) {
                float e = as[csr_src[beg + t]] + ad_d;
                e = (e > 0.f) ? e : NEG_SLOPE * e;
                m = fmaxf(m, e);
            }
        }
        // wave combine (guarded against -inf/-inf)
        #pragma unroll
        for (int off = 32; off > 0; off >>= 1) {
            float mo = __shfl_xor(m, off, 64);
            float so = __shfl_xor(ssum, off, 64);
            float nm = fmaxf(m, mo);
            float f1 = (m == nm) ? 1.f : __expf(m - nm);
            float f2 = (mo == nm) ? 1.f : __expf(mo - nm);
            ssum = ssum * f1 + so * f2;
            m = nm;
        }
        if (!small) {
            ssum = 0.f;
            for (int t = lane; t < deg; t += 64) {
                float e = as[csr_src[beg + t]] + ad_d;
                e = (e > 0.f) ? e : NEG_SLOPE * e;
                ssum += __expf(e - m);
            }
            #pragma unroll
            for (int off = 32; off > 0; off >>= 1) ssum += __shfl_xor(ssum, off, 64);
        }
        inv = 1.f / (ssum + SM_EPS);
        if (small) {
            // convert cached e -> normalized weight (lane-distributed exp)
            for (int t = lane; t < deg; t += 64) {
                float e = __uint_as_float(cache[w][t].y);
                cache[w][t].y = __float_as_uint(__expf(e - m) * inv);
            }
        }
    }
    __syncthreads();   // cross-lane LDS visibility (all threads reach)

    if (active) {
        const int c2 = lane << 1;
        float a0 = 0.f, a1 = 0.f;
        if (small) {
            int t = 0;
            for (; t + 4 <= deg; t += 4) {
                uint2 p0 = cache[w][t],     p1 = cache[w][t + 1];
                uint2 p2 = cache[w][t + 2], p3 = cache[w][t + 3];
                uint32 u0 = *(const uint32*)&hb[(size_t)p0.x * C + c2];
                uint32 u1 = *(const uint32*)&hb[(size_t)p1.x * C + c2];
                uint32 u2 = *(const uint32*)&hb[(size_t)p2.x * C + c2];
                uint32 u3 = *(const uint32*)&hb[(size_t)p3.x * C + c2];
                float w0 = __uint_as_float(p0.y), w1 = __uint_as_float(p1.y);
                float w2 = __uint_as_float(p2.y), w3 = __uint_as_float(p3.y);
                a0 += __uint_as_float(u0 << 16) * w0 + __uint_as_float(u1 << 16) * w1
                    + __uint_as_float(u2 << 16) * w2 + __uint_as_float(u3 << 16) * w3;
                a1 += __uint_as_float(u0 & 0xffff0000u) * w0 + __uint_as_float(u1 & 0xffff0000u) * w1
                    + __uint_as_float(u2 & 0xffff0000u) * w2 + __uint_as_float(u3 & 0xffff0000u) * w3;
            }
            for (; t < deg; ++t) {
                uint2 p0 = cache[w][t];
                uint32 u0 = *(const uint32*)&hb[(size_t)p0.x * C + c2];
                float w0 = __uint_as_float(p0.y);
                a0 += __uint_as_float(u0 << 16) * w0;
                a1 += __uint_as_float(u0 & 0xffff0000u) * w0;
            }
        } else {
            for (int t = 0; t < deg; ++t) {
                int s = csr_src[beg + t];
                float e = as[s] + ad_d;
                e = (e > 0.f) ? e : NEG_SLOPE * e;
                float w0 = __expf(e - m) * inv;
                uint32 u0 = *(const uint32*)&hb[(size_t)s * C + c2];
                a0 += __uint_as_float(u0 << 16) * w0;
                a1 += __uint_as_float(u0 & 0xffff0000u) * w0;
            }
        }
        float2 b2 = *(const float2*)&bias[c2];
        a0 = fmaxf(a0 + b2.x, 0.f);
        a1 = fmaxf(a1 + b2.y, 0.f);
        *(float2*)&out[(size_t)d * C + c2] = make_float2(a0, a1);
    }
}

extern "C" void kernel_launch(void* const* d_in, const int* in_sizes, int n_in,
                              void* d_out, int out_size, void* d_ws, size_t ws_size,
                              hipStream_t stream) {
    const float* x     = (const float*)d_in[0];
    const float* W     = (const float*)d_in[1];
    const float* a_src = (const float*)d_in[2];
    const float* a_dst = (const float*)d_in[3];
    const float* bias  = (const float*)d_in[4];
    const int*   edge  = (const int*)d_in[5];

    const int N = in_sizes[0] / C;
    const int E = in_sizes[5] / 2;
    const int total = E + N;
    const int* src = edge;
    const int* dst = edge + E;
    float* out = (float*)d_out;

    const int NB = (N + BKT_MASK) >> BKT_SHIFT;

    // workspace (4B units):
    // hb[N*C/2] | as[N] | ad[N] | row_start[N+1] | packed[total] | csr_src[total]
    // | bucket_cnt[NB] | bucket_off[NB+1] | bucket_cursor[NB]
    float* ws = (float*)d_ws;
    unsigned short* hb = (unsigned short*)ws;
    float* as = (float*)(hb + (size_t)N * C);
    float* ad = as + N;
    int* row_start     = (int*)(ad + N);
    uint32* packed     = (uint32*)(row_start + (N + 1));
    int* csr_src       = (int*)(packed + total);
    int* bucket_cnt    = csr_src + total;
    int* bucket_off    = bucket_cnt + NB;
    int* bucket_cursor = bucket_off + (NB + 1);

    zero_kernel<<<(NB + 255) / 256, 256, 0, stream>>>(bucket_cnt, NB);
    gemm_mfma_kernel<<<(N + 63) / 64, 256, 0, stream>>>(x, W, a_src, a_dst, hb, as, ad, N);
    hist_kernel<<<256, 256, 0, stream>>>(dst, bucket_cnt, E, total, NB);
    scan_off_kernel<<<1, 256, 0, stream>>>(bucket_cnt, bucket_off, bucket_cursor,
                                           row_start, NB, N, total);
    bin_kernel<<<(total + BIN_CHUNK - 1) / BIN_CHUNK, 256, 0, stream>>>(
        src, dst, bucket_cursor, packed, E, total, NB);
    build_kernel<<<NB, 256, 0, stream>>>(packed, bucket_off, row_start, csr_src, N);
    gather_kernel<<<(N + 3) / 4, 256, 0, stream>>>(csr_src, row_start, as, ad, hb, bias, out, N);
}